// Round 2
// baseline (201.422 us; speedup 1.0000x reference)
//
#include <hip/hip_runtime.h>
#include <math.h>

// Cross-entropy: loss = mean_b( logsumexp(x[b,:]) - x[b, t_b] )
// B=8192, V=32000 fp32. HBM-bound: ~1.05 GB read once.
// Structure: one WAVE per row (no barriers, no LDS), 4 rows per 256-thread
// block, grid=2048 = 8 blocks/CU (exactly one full-occupancy round).
// 4 independent (m,s) accumulator chains (one per float4 component) for ILP.

#define LOG2E 1.4426950408889634f
#define LN2   0.6931471805599453f

__global__ __launch_bounds__(256) void ce_row_kernel(const float* __restrict__ x,
                                                     const int* __restrict__ tgt,
                                                     float* __restrict__ row_loss,
                                                     int V, int B) {
    const int wave = threadIdx.x >> 6;
    const int lane = threadIdx.x & 63;
    const int row  = (blockIdx.x << 2) + wave;
    if (row >= B) return;

    const float* __restrict__ xr = x + (size_t)row * (size_t)V;
    const float4* __restrict__ xv = (const float4*)xr;
    const int nvec = V >> 2;          // 8000; per-lane trip count 125 = 5*25

    // Work in log2 domain: w = x * log2e, so each term is exp2(w - max).
    float m0 = -INFINITY, m1 = -INFINITY, m2 = -INFINITY, m3 = -INFINITY;
    float s0 = 0.f, s1 = 0.f, s2 = 0.f, s3 = 0.f;

    #pragma unroll 5
    for (int i = lane; i < nvec; i += 64) {
        float4 v = xv[i];
        float w0 = v.x * LOG2E, w1 = v.y * LOG2E,
              w2 = v.z * LOG2E, w3 = v.w * LOG2E;
        float n0 = fmaxf(m0, w0);
        s0 = s0 * exp2f(m0 - n0) + exp2f(w0 - n0); m0 = n0;
        float n1 = fmaxf(m1, w1);
        s1 = s1 * exp2f(m1 - n1) + exp2f(w1 - n1); m1 = n1;
        float n2 = fmaxf(m2, w2);
        s2 = s2 * exp2f(m2 - n2) + exp2f(w2 - n2); m2 = n2;
        float n3 = fmaxf(m3, w3);
        s3 = s3 * exp2f(m3 - n3) + exp2f(w3 - n3); m3 = n3;
    }

    // Merge the 4 component chains.
    float M = fmaxf(fmaxf(m0, m1), fmaxf(m2, m3));
    float S = s0 * exp2f(m0 - M) + s1 * exp2f(m1 - M)
            + s2 * exp2f(m2 - M) + s3 * exp2f(m3 - M);

    // In-wave butterfly merge (64 lanes).
    #pragma unroll
    for (int off = 1; off < 64; off <<= 1) {
        float om = __shfl_xor(M, off);
        float os = __shfl_xor(S, off);
        float mn = fmaxf(M, om);
        S = S * exp2f(M - mn) + os * exp2f(om - mn);
        M = mn;
    }

    if (lane == 0) {
        float lse = (M + log2f(S)) * LN2;   // back to natural-log domain
        row_loss[row] = lse - xr[tgt[row]];
    }
}

// Deterministic single-block reduction of per-row losses -> mean.
__global__ __launch_bounds__(256) void ce_reduce_kernel(const float* __restrict__ row_loss,
                                                        float* __restrict__ out, int B) {
    float acc = 0.0f;
    for (int i = threadIdx.x; i < B; i += 256) acc += row_loss[i];
    #pragma unroll
    for (int off = 1; off < 64; off <<= 1) acc += __shfl_xor(acc, off);
    __shared__ float sa[4];
    if ((threadIdx.x & 63) == 0) sa[threadIdx.x >> 6] = acc;
    __syncthreads();
    if (threadIdx.x == 0) out[0] = (sa[0] + sa[1] + sa[2] + sa[3]) / (float)B;
}

extern "C" void kernel_launch(void* const* d_in, const int* in_sizes, int n_in,
                              void* d_out, int out_size, void* d_ws, size_t ws_size,
                              hipStream_t stream) {
    const float* x = (const float*)d_in[0];
    const int* tgt = (const int*)d_in[1];
    float* out = (float*)d_out;
    float* ws = (float*)d_ws;   // B floats of per-row loss

    const int B = in_sizes[1];                 // 8192
    const int V = in_sizes[0] / B;             // 32000

    ce_row_kernel<<<(B + 3) / 4, 256, 0, stream>>>(x, tgt, ws, V, B);
    ce_reduce_kernel<<<1, 256, 0, stream>>>(ws, out, B);
}

// Round 4
// 176.235 us; speedup vs baseline: 1.1429x; 1.1429x over previous
//
#include <hip/hip_runtime.h>
#include <math.h>

// Cross-entropy: loss = mean_b( logsumexp(x[b,:]) - x[b, t_b] )
// B=8192, V=32000 fp32. HBM-bound: ~1.05 GB read once.
// Structure (round-1, best known): one 256-thread block per row.
// Round-4 change: non-temporal loads via clang ext_vector_type (the builtin
// rejects HIP_vector_type structs) -> global_load_dwordx4 ... nt.

#define LOG2E 1.4426950408889634f
#define LN2   0.6931471805599453f

typedef float floatx4 __attribute__((ext_vector_type(4)));

__global__ __launch_bounds__(256) void ce_row_kernel(const float* __restrict__ x,
                                                     const int* __restrict__ tgt,
                                                     float* __restrict__ row_loss,
                                                     int V) {
    const int row = blockIdx.x;
    const float* __restrict__ xr = x + (size_t)row * (size_t)V;
    const int tid = threadIdx.x;

    const int nvec = V >> 2;                 // 8000 (V % 4 == 0)
    const floatx4* __restrict__ xv = (const floatx4*)xr;

    // Online logsumexp in log2 domain; 4 independent component chains for ILP.
    float m0 = -INFINITY, m1 = -INFINITY, m2 = -INFINITY, m3 = -INFINITY;
    float s0 = 0.f, s1 = 0.f, s2 = 0.f, s3 = 0.f;

    for (int i = tid; i < nvec; i += 256) {
        floatx4 v = __builtin_nontemporal_load(&xv[i]);
        float w0 = v.x * LOG2E, w1 = v.y * LOG2E,
              w2 = v.z * LOG2E, w3 = v.w * LOG2E;
        float n0 = fmaxf(m0, w0);
        s0 = s0 * exp2f(m0 - n0) + exp2f(w0 - n0); m0 = n0;
        float n1 = fmaxf(m1, w1);
        s1 = s1 * exp2f(m1 - n1) + exp2f(w1 - n1); m1 = n1;
        float n2 = fmaxf(m2, w2);
        s2 = s2 * exp2f(m2 - n2) + exp2f(w2 - n2); m2 = n2;
        float n3 = fmaxf(m3, w3);
        s3 = s3 * exp2f(m3 - n3) + exp2f(w3 - n3); m3 = n3;
    }

    // Merge the 4 component chains.
    float M = fmaxf(fmaxf(m0, m1), fmaxf(m2, m3));
    float S = s0 * exp2f(m0 - M) + s1 * exp2f(m1 - M)
            + s2 * exp2f(m2 - M) + s3 * exp2f(m3 - M);

    // Wave (64-lane) butterfly merge.
    #pragma unroll
    for (int off = 1; off < 64; off <<= 1) {
        float om = __shfl_xor(M, off);
        float os = __shfl_xor(S, off);
        float mn = fmaxf(M, om);
        S = S * exp2f(M - mn) + os * exp2f(om - mn);
        M = mn;
    }

    // Cross-wave merge (4 waves).
    __shared__ float sm[4], ss[4];
    const int wave = tid >> 6;
    if ((tid & 63) == 0) { sm[wave] = M; ss[wave] = S; }
    __syncthreads();

    if (tid == 0) {
        float Mf = sm[0], Sf = ss[0];
        #pragma unroll
        for (int w = 1; w < 4; ++w) {
            float om = sm[w], os = ss[w];
            float mn = fmaxf(Mf, om);
            Sf = Sf * exp2f(Mf - mn) + os * exp2f(om - mn);
            Mf = mn;
        }
        float lse = (Mf + log2f(Sf)) * LN2;   // back to natural log
        row_loss[row] = lse - xr[tgt[row]];
    }
}

// Deterministic single-block reduction of per-row losses -> mean.
__global__ __launch_bounds__(256) void ce_reduce_kernel(const float* __restrict__ row_loss,
                                                        float* __restrict__ out, int B) {
    float acc = 0.0f;
    for (int i = threadIdx.x; i < B; i += 256) acc += row_loss[i];
    #pragma unroll
    for (int off = 1; off < 64; off <<= 1) acc += __shfl_xor(acc, off);
    __shared__ float sa[4];
    if ((threadIdx.x & 63) == 0) sa[threadIdx.x >> 6] = acc;
    __syncthreads();
    if (threadIdx.x == 0) out[0] = (sa[0] + sa[1] + sa[2] + sa[3]) / (float)B;
}

extern "C" void kernel_launch(void* const* d_in, const int* in_sizes, int n_in,
                              void* d_out, int out_size, void* d_ws, size_t ws_size,
                              hipStream_t stream) {
    const float* x = (const float*)d_in[0];
    const int* tgt = (const int*)d_in[1];
    float* out = (float*)d_out;
    float* ws = (float*)d_ws;   // B floats of per-row loss

    const int B = in_sizes[1];                 // 8192
    const int V = in_sizes[0] / B;             // 32000

    ce_row_kernel<<<B, 256, 0, stream>>>(x, tgt, ws, V);
    ce_reduce_kernel<<<1, 256, 0, stream>>>(ws, out, B);
}